// Round 11
// baseline (474.684 us; speedup 1.0000x reference)
//
#include <hip/hip_runtime.h>

#define C 512
#define HW 4096
#define EPSV 1e-5f

typedef _Float16 fp16x8 __attribute__((ext_vector_type(8)));
typedef _Float16 fp16x4 __attribute__((ext_vector_type(4)));
typedef float f32x4 __attribute__((ext_vector_type(4)));

// ---- workspace layout (bytes) ----
#define OFF_MC    (0)
#define OFF_RC    (8192)
#define OFF_MS    (16384)
#define OFF_RS    (24576)
#define OFF_BETAF (32768)
#define OFF_V     (40960)
#define OFF_BZ    (49152)
#define OFF_T     (65536)                      // t[b][m] f32, 64 KB
#define OFF_SP    (131072)                     // stats partials (2MB); reused as As f16 after finalize
#define OFF_A     (OFF_SP + 2097152)           // 1 MB (A f32)
#define OFF_WZ    (OFF_A + 1048576)            // 1 MB (Wz f16 FT, 512KB used)
#define OFF_XCT   (OFF_WZ + 1048576)           // 16 MB (fragment-tiled; reused as Scl after qk)
#define OFF_XST   (OFF_XCT + 16777216)         // 16 MB (fragment-tiled)
#define OFF_KT    (OFF_XST + 16777216)         // 16 MB (fragment-tiled)
#define OFF_HM    (OFF_KT + 16777216)          // 16 MB (fragment-tiled Hp layout)
#define OFF_ML    (OFF_HM + 16777216)          // float2[4][4096][64] = 8 MB
#define OFF_S     (OFF_ML + 8388608)           // f16 [4] fragment-tiled [4096][4096] = 128 MB
// total ~= 204 MB

// Fragment-tiled layout for transposed f16 tensors (xcT, xsT, Kt) and 512x512
// operands (As, Wz): elem (row n, col c) ->
//   ((n>>4)*16 + (c>>5))*512 + ((c>>3)&3)*128 + (n&15)*8 + (c&7)
#define FT_IDX(n, c) ((((size_t)((n) >> 4) * 16 + ((c) >> 5)) * 512) + \
                      ((((c) >> 3) & 3) * 128) + (((n) & 15) * 8) + ((c) & 7))

// S fragment-tiled (per batch, n,m in [0,4096)):
#define SFT_IDX(n, m) ((((size_t)((n) >> 4) * 128 + ((m) >> 5)) * 512) + \
                       ((((m) >> 3) & 3) * 128) + (((n) & 15) * 8) + ((m) & 7))

// Hp tiled layout (per batch b): (co, m) at ((co>>4)*512 + (m>>3))*128 + (co&15)*8 + (m&7)

// Stats partials: float2 part[64 chunk][4096 ch] — chunk-major so BOTH the
// per-tile writer (64 consecutive ch) and the finalize reader (lane = ch)
// are coalesced.

// ---------------------------------------------------------------------------
// 1) fused transpose + f16 cast + partial stats. COALESCED fp32 reads
//    (4 x 256B segments per instr) + LDS partial-sum stats reduce.
// ---------------------------------------------------------------------------
__global__ void transpose_stats_kernel(const float* __restrict__ xc, const float* __restrict__ xs,
                                       char* __restrict__ ws)
{
    int bx = blockIdx.x;                  // 4096 = 2 * 4 * 8 * 64
    int tensor = bx >> 11, b = (bx >> 9) & 3, c0 = ((bx >> 6) & 7) * 64, n0 = (bx & 63) * 64;
    const float* src = tensor ? xs : xc;
    _Float16* dst = (_Float16*)(ws + (tensor ? OFF_XST : OFF_XCT));
    float2* part = (float2*)(ws + OFF_SP);

    __shared__ _Float16 tile[64][72];
    __shared__ float pS[64][16], pSS[64][16];

    int tid = threadIdx.x, w = tid >> 6, lane = tid & 63, cq = lane >> 4, l16 = lane & 15;
    #pragma unroll
    for (int k = 0; k < 4; k++) {
        int cr = w * 16 + k * 4 + cq;                 // c offset within tile (bijective over k,w,cq)
        int nf = l16 * 4;                             // n offset within tile
        float4 v = *(const float4*)(src + ((size_t)(b * C + c0 + cr)) * HW + n0 + nf);
        pS[cr][l16] = v.x + v.y + v.z + v.w;
        pSS[cr][l16] = v.x * v.x + v.y * v.y + v.z * v.z + v.w * v.w;
        tile[nf][cr] = (_Float16)v.x; tile[nf + 1][cr] = (_Float16)v.y;
        tile[nf + 2][cr] = (_Float16)v.z; tile[nf + 3][cr] = (_Float16)v.w;
    }
    __syncthreads();
    if (tid < 64) {
        float S = 0.f, SS = 0.f;
        #pragma unroll
        for (int j = 0; j < 16; j++) { S += pS[tid][j]; SS += pSS[tid][j]; }
        part[((size_t)(n0 >> 6)) * 4096 + (tensor * 4 + b) * 512 + c0 + tid] =
            make_float2(S, SS);
    }
    _Float16* dstB = dst + (size_t)b * HW * C;
    #pragma unroll
    for (int i = 0; i < 2; i++) {
        int g = tid + i * 256, row = g >> 3, c8 = (g & 7) * 8;
        int n = n0 + row, c = c0 + c8;
        *(fp16x8*)&dstB[FT_IDX(n, c)] = *(const fp16x8*)&tile[row][c8];
    }
}

// ---------------------------------------------------------------------------
// 1b) finalize stats — chunk-major partials: lane = ch, fully coalesced.
// ---------------------------------------------------------------------------
__global__ void finalize_stats_kernel(char* __restrict__ ws)
{
    int ch = blockIdx.x * 256 + threadIdx.x;       // 16 blocks -> 4096 channels
    const float2* part = (const float2*)(ws + OFF_SP);
    float S = 0.f, SS = 0.f;
    for (int k = 0; k < 64; k++) { float2 v = part[(size_t)k * 4096 + ch]; S += v.x; SS += v.y; }
    int tensor = ch >> 11, rem = ch & 2047;
    float m = S / (float)HW;
    float var = (SS - S * m) / (float)(HW - 1) + EPSV;   // unbiased (n-1) + EPS
    ((float*)(ws + (tensor ? OFF_MS : OFF_MC)))[rem] = m;
    ((float*)(ws + (tensor ? OFF_RS : OFF_RC)))[rem] = rsqrtf(var);
}

// ---------------------------------------------------------------------------
// 2) A = Wf^T Wg (f32) and Wz = Wo Wh (f16 FT). Loads lane-coalesced.
// ---------------------------------------------------------------------------
__global__ void precompute_kernel(const float* __restrict__ Wf, const float* __restrict__ Wg,
                                  const float* __restrict__ Wo, const float* __restrict__ Wh,
                                  char* __restrict__ ws)
{
    float* A = (float*)(ws + OFF_A);
    _Float16* Wz16 = (_Float16*)(ws + OFF_WZ);
    int bx = blockIdx.x, t = threadIdx.x;
    bool isA = bx < 256;
    int r0 = (isA ? bx : bx - 256) * 2;
    float a00 = 0.f, a01 = 0.f, a10 = 0.f, a11 = 0.f;
    for (int k = 0; k < C; k++) {
        float r0v, r1v, c0v, c1v;
        if (isA) {                           // A[i][j] = sum_co Wf[co][i]*Wg[co][j]
            r0v = Wf[k * C + r0]; r1v = Wf[k * C + r0 + 1];
            c0v = Wg[k * C + t];  c1v = Wg[k * C + t + 256];
        } else {                             // Wz[o][j] = sum_i Wo[o][i]*Wh[i][j]
            r0v = Wo[r0 * C + k]; r1v = Wo[(r0 + 1) * C + k];
            c0v = Wh[k * C + t];  c1v = Wh[k * C + t + 256];
        }
        a00 += r0v * c0v; a01 += r0v * c1v;
        a10 += r1v * c0v; a11 += r1v * c1v;
    }
    if (isA) {
        A[r0 * C + t] = a00;       A[r0 * C + t + 256] = a01;
        A[(r0 + 1) * C + t] = a10; A[(r0 + 1) * C + t + 256] = a11;
    } else {
        Wz16[FT_IDX(r0, t)] = (_Float16)a00;
        Wz16[FT_IDX(r0, t + 256)] = (_Float16)a01;
        Wz16[FT_IDX(r0 + 1, t)] = (_Float16)a10;
        Wz16[FT_IDX(r0 + 1, t + 256)] = (_Float16)a11;
    }
}

// ---------------------------------------------------------------------------
// 2a) betaf + bz — one output per WAVE; lanes split i contiguously (2KB
//     coalesced row reads) + 6-level shuffle reduce. 640 blocks x 4 waves.
// ---------------------------------------------------------------------------
__global__ void __launch_bounds__(256) vecprep_kernel(const float* __restrict__ Wf,
                                                      const float* __restrict__ bf,
                                                      const float* __restrict__ Wo,
                                                      const float* __restrict__ bh,
                                                      char* __restrict__ ws)
{
    const float* mc = (const float*)(ws + OFF_MC);
    const float* rc = (const float*)(ws + OFF_RC);
    float* betaf = (float*)(ws + OFF_BETAF);
    float* bz = (float*)(ws + OFF_BZ);

    int o = blockIdx.x * 4 + (threadIdx.x >> 6);   // 0..2559
    int lane = threadIdx.x & 63;
    float acc = 0.f;
    if (o < 2048) {                                // betaf[b][co]
        int b = o >> 9, co = o & 511;
        const float* wr = Wf + (size_t)co * C + lane * 8;
        const float* mp = mc + b * C + lane * 8;
        const float* rp = rc + b * C + lane * 8;
        #pragma unroll
        for (int e = 0; e < 8; e++) acc += wr[e] * mp[e] * rp[e];
    } else {                                       // bz[co]
        int co = o - 2048;
        const float* wr = Wo + (size_t)co * C + lane * 8;
        const float* bp = bh + lane * 8;
        #pragma unroll
        for (int e = 0; e < 8; e++) acc += wr[e] * bp[e];
    }
    acc += __shfl_xor(acc, 1);
    acc += __shfl_xor(acc, 2);
    acc += __shfl_xor(acc, 4);
    acc += __shfl_xor(acc, 8);
    acc += __shfl_xor(acc, 16);
    acc += __shfl_xor(acc, 32);
    if (lane == 0) {
        if (o < 2048) betaf[o] = bf[o & 511] - acc;
        else bz[o - 2048] = acc;
    }
}

// ---------------------------------------------------------------------------
// 2b) As[b] = diag(rc_b) * A * diag(rs_b), f16 FT (into dead SP buf).
//     LDS-staged: coalesced 2KB row loads, coalesced FT stores.
// ---------------------------------------------------------------------------
__global__ void __launch_bounds__(256) scaleA_kernel(char* __restrict__ ws)
{
    const float* __restrict__ A = (const float*)(ws + OFF_A);
    const float* __restrict__ rc = (const float*)(ws + OFF_RC);
    const float* __restrict__ rs = (const float*)(ws + OFF_RS);
    _Float16* __restrict__ As = (_Float16*)(ws + OFF_SP);

    __shared__ float At[16][516];
    __shared__ float rsl[512];
    __shared__ float rcl[16];

    int bx = blockIdx.x;                 // 128 = 4 b * 32 r16-groups
    int b = bx >> 5, r16 = bx & 31;
    int r0 = r16 * 16;
    int t = threadIdx.x;

    rsl[t] = rs[b * C + t];
    rsl[t + 256] = rs[b * C + t + 256];
    if (t < 16) rcl[t] = rc[b * C + r0 + t];
    {
        int row = t >> 4, cb = (t & 15) * 32;
        const float* src = A + (size_t)(r0 + row) * C + cb;
        #pragma unroll
        for (int k = 0; k < 8; k++) {
            float4 v = *(const float4*)(src + k * 4);
            At[row][cb + k * 4] = v.x; At[row][cb + k * 4 + 1] = v.y;
            At[row][cb + k * 4 + 2] = v.z; At[row][cb + k * 4 + 3] = v.w;
        }
    }
    __syncthreads();

    _Float16* AsB = As + (size_t)b * 262144 + (size_t)r16 * 8192;
    #pragma unroll
    for (int round = 0; round < 4; round++) {
        int flat = round * 2048 + t * 8;           // f16 units within 16KB region
        int cb4 = flat >> 9, rem = flat & 511;
        int low6 = rem >> 3;
        int q = low6 >> 4, l16 = low6 & 15;
        int cbase = cb4 * 32 + q * 8;
        float rcv = rcl[l16];
        fp16x8 o;
        #pragma unroll
        for (int e = 0; e < 8; e++)
            o[e] = (_Float16)(At[l16][cbase + e] * rcv * rsl[cbase + e]);
        *(fp16x8*)&AsB[flat] = o;
    }
}

// ---------------------------------------------------------------------------
// 2c) v[b][j] = rs[b][j] * sum_co betaf[b][co]*Wg[co][j] — LDS-tiled
//     (coalesced row loads of Wg; column dot done in LDS). 32 blocks.
// ---------------------------------------------------------------------------
__global__ void __launch_bounds__(256) precompute_v_kernel(const float* __restrict__ Wg,
                                                           char* __restrict__ ws)
{
    const float* betaf = (const float*)(ws + OFF_BETAF);
    const float* rs = (const float*)(ws + OFF_RS);
    float* v = (float*)(ws + OFF_V);

    __shared__ float bet[512];
    __shared__ float Wgt[64][68];
    __shared__ float pacc[4][64];
    __shared__ float rsl[64];

    int bx = blockIdx.x;                 // 32 = 4 b * 8 j-groups
    int b = bx >> 3, j0 = (bx & 7) * 64;
    int t = threadIdx.x;

    bet[t] = betaf[b * C + t];
    bet[t + 256] = betaf[b * C + t + 256];
    if (t < 64) rsl[t] = rs[b * C + j0 + t];

    int j = t & 63, g = t >> 6;
    float acc = 0.f;
    for (int ch = 0; ch < 8; ch++) {
        __syncthreads();
        // stage Wg[ch*64 .. +64][j0 .. +64] (64 x 256B rows, coalesced)
        {
            int row = t >> 2, cq = (t & 3) * 16;
            const float* src = Wg + (size_t)(ch * 64 + row) * C + j0 + cq;
            #pragma unroll
            for (int k = 0; k < 4; k++) {
                float4 w4 = *(const float4*)(src + k * 4);
                Wgt[row][cq + k * 4] = w4.x; Wgt[row][cq + k * 4 + 1] = w4.y;
                Wgt[row][cq + k * 4 + 2] = w4.z; Wgt[row][cq + k * 4 + 3] = w4.w;
            }
        }
        __syncthreads();
        #pragma unroll
        for (int r2 = 0; r2 < 16; r2++) {
            int col = g * 16 + r2;
            acc += bet[ch * 64 + col] * Wgt[col][j];
        }
    }
    pacc[g][j] = acc;
    __syncthreads();
    if (t < 64)
        v[b * C + j0 + t] = rsl[t] * (pacc[0][t] + pacc[1][t] + pacc[2][t] + pacc[3][t]);
}

// ---------------------------------------------------------------------------
// 3) fused prep GEMM -> Kt (f16 FT) and Hp (f16 tiled). All loads wave-linear.
// ---------------------------------------------------------------------------
__global__ void __launch_bounds__(256) prep_gemm_kernel(char* __restrict__ ws)
{
    const _Float16* __restrict__ As = (const _Float16*)(ws + OFF_SP);
    const _Float16* __restrict__ Wz16 = (const _Float16*)(ws + OFF_WZ);
    const float* __restrict__ bz = (const float*)(ws + OFF_BZ);
    const _Float16* __restrict__ xsT = (const _Float16*)(ws + OFF_XST);
    _Float16* __restrict__ Kt = (_Float16*)(ws + OFF_KT);
    _Float16* __restrict__ Hp = (_Float16*)(ws + OFF_HM);

    int bx = blockIdx.x;                 // 1024 = 4b * 8 rowblk * 32 mblk
    int b = bx & 3, rest = bx >> 2;
    int r128 = rest >> 5, mb = rest & 31;
    int r0 = r128 * 128, m0 = mb * 128;
    int w = threadIdx.x >> 6, lane = threadIdx.x & 63, q = lane >> 4, l16 = lane & 15;
    int wr = (w & 1) * 64, wm = (w >> 1) * 64;
    bool isK = (r0 < 512);
    int rbase = (isK ? r0 : r0 - 512) + wr;

    f32x4 zz = {0.f, 0.f, 0.f, 0.f};
    f32x4 acc[4][4];
    #pragma unroll
    for (int rt = 0; rt < 4; rt++)
        #pragma unroll
        for (int mt = 0; mt < 4; mt++) acc[rt][mt] = zz;

    const _Float16* ap = (isK ? As + (size_t)b * 262144 : Wz16)
                         + (size_t)(rbase >> 4) * 8192 + q * 128 + l16 * 8;
    const _Float16* xb = xsT + (size_t)b * HW * C
                             + (size_t)((m0 + wm) >> 4) * 8192 + q * 128 + l16 * 8;

    for (int ks = 0; ks < 16; ks++) {
        fp16x8 afr[4], bfr[4];
        #pragma unroll
        for (int rt = 0; rt < 4; rt++)
            afr[rt] = *(const fp16x8*)(ap + (size_t)rt * 8192 + ks * 512);
        #pragma unroll
        for (int mt = 0; mt < 4; mt++)
            bfr[mt] = *(const fp16x8*)(xb + (size_t)(mt * 16 + ks) * 512);
        #pragma unroll
        for (int rt = 0; rt < 4; rt++)
            #pragma unroll
            for (int mt = 0; mt < 4; mt++)
                acc[rt][mt] = __builtin_amdgcn_mfma_f32_16x16x32_f16(afr[rt], bfr[mt], acc[rt][mt], 0, 0, 0);
    }

    if (isK) {
        _Float16* KtB = Kt + (size_t)b * HW * C;
        #pragma unroll
        for (int rt = 0; rt < 4; rt++)
            #pragma unroll
            for (int mt = 0; mt < 4; mt++) {
                int m = m0 + wm + mt * 16 + l16;
                int cb = r0 + wr + rt * 16 + q * 4;
                fp16x4 h;
                h[0] = (_Float16)acc[rt][mt][0]; h[1] = (_Float16)acc[rt][mt][1];
                h[2] = (_Float16)acc[rt][mt][2]; h[3] = (_Float16)acc[rt][mt][3];
                *(fp16x4*)&KtB[FT_IDX(m, cb)] = h;
            }
    } else {
        _Float16* HpB = Hp + (size_t)b * 2097152;
        #pragma unroll
        for (int rt = 0; rt < 4; rt++) {
            float bzv[4];
            #pragma unroll
            for (int reg = 0; reg < 4; reg++) bzv[reg] = bz[rbase + rt * 16 + q * 4 + reg];
            #pragma unroll
            for (int mt = 0; mt < 4; mt++) {
                int m = m0 + wm + mt * 16 + l16;
                int mbase = (m >> 3) * 128 + (m & 7);
                #pragma unroll
                for (int reg = 0; reg < 4; reg++) {
                    int co = rbase + rt * 16 + q * 4 + reg;
                    HpB[(size_t)(co >> 4) * 65536 + mbase + (co & 15) * 8] =
                        (_Float16)(acc[rt][mt][reg] + bzv[reg]);
                }
            }
        }
    }
}

// ---------------------------------------------------------------------------
// 4) t[b][m] = sum_j v[b][j] * xsT[b][m][j] — wave-linear FT loads.
// ---------------------------------------------------------------------------
__global__ void t_kernel(char* __restrict__ ws)
{
    const float* v = (const float*)(ws + OFF_V);
    const _Float16* __restrict__ xsT = (const _Float16*)(ws + OFF_XST);
    float* tG = (float*)(ws + OFF_T);
    int bx = blockIdx.x;                      // 256 = 4 b * 64 mblk(64m)
    int b = bx >> 6, mb = bx & 63;
    int tid = threadIdx.x, w = tid >> 6, lane = tid & 63, q = lane >> 4, l16 = lane & 15;
    int M16 = mb * 4 + w;                     // m-subtile; m = M16*16 + l16
    const _Float16* p = xsT + (size_t)b * HW * C + (size_t)M16 * 8192 + q * 128 + l16 * 8;
    const float* vp = v + b * C + q * 8;
    float acc = 0.f;
    #pragma unroll
    for (int st = 0; st < 16; st++) {
        fp16x8 xv = *(const fp16x8*)(p + st * 512);
        float4 v0 = *(const float4*)(vp + st * 32);
        float4 v1 = *(const float4*)(vp + st * 32 + 4);
        acc += (float)xv[0] * v0.x + (float)xv[1] * v0.y + (float)xv[2] * v0.z + (float)xv[3] * v0.w
             + (float)xv[4] * v1.x + (float)xv[5] * v1.y + (float)xv[6] * v1.z + (float)xv[7] * v1.w;
    }
    acc += __shfl_xor(acc, 16);
    acc += __shfl_xor(acc, 32);
    if (q == 0) tG[b * HW + M16 * 16 + l16] = acc;
}

// ---------------------------------------------------------------------------
// 5) pass A: S-tile = Q @ Kt^T (128x128, K=512) + t[m], LDS-STAGED (r10).
// ---------------------------------------------------------------------------
__global__ void __launch_bounds__(256, 4) qk_kernel(char* __restrict__ ws)
{
    const _Float16* __restrict__ xcT = (const _Float16*)(ws + OFF_XCT);
    const _Float16* __restrict__ Kt = (const _Float16*)(ws + OFF_KT);
    const float* __restrict__ tG = (const float*)(ws + OFF_T);
    float2* __restrict__ ML = (float2*)(ws + OFF_ML);
    _Float16* __restrict__ Sg = (_Float16*)(ws + OFF_S);

    int bx = blockIdx.x;                  // 4096: low3 = b*2+mhi (XCD-pinned)
    int b = (bx >> 1) & 3, mhi = bx & 1;
    int rest = bx >> 3, mlo = rest & 15, ntile = rest >> 4;
    int m0 = (mhi * 16 + mlo) * 128, n0 = ntile * 128;
    int tid = threadIdx.x, w = tid >> 6, lane = tid & 63, q = lane >> 4, l16 = lane & 15;
    int wn = (w & 1) * 64, wm = (w >> 1) * 64;

    __shared__ char lbuf[36864];          // loop: Ax[2][8KB]+Bx[2][8KB]; epilogue: Pl
    _Float16* Ax0 = (_Float16*)lbuf;                  // [2][4096]
    _Float16* Bx0 = (_Float16*)(lbuf + 16384);        // [2][4096]

    int st = tid >> 5, so = (tid & 31) * 16;
    const _Float16* gA = xcT + (size_t)b * HW * C + ((size_t)(n0 >> 4) + st) * 8192 + so;
    const _Float16* gB = Kt + (size_t)b * HW * C + ((size_t)(m0 >> 4) + st) * 8192 + so;

    {
        fp16x8 a0 = *(const fp16x8*)(gA);
        fp16x8 a1 = *(const fp16x8*)(gA + 8);
        fp16x8 b0 = *(const fp16x8*)(gB);
        fp16x8 b1 = *(const fp16x8*)(gB + 8);
        *(fp16x8*)&Ax0[tid * 16] = a0; *(fp16x8*)&Ax0[tid * 16 + 8] = a1;
        *(fp16x8*)&Bx0[tid * 16] = b0; *(fp16x8*)&Bx0[tid * 16 + 8] = b1;
    }
    __syncthreads();

    f32x4 zz = {0.f, 0.f, 0.f, 0.f};
    f32x4 acc[4][4];
    #pragma unroll
    for (int nt = 0; nt < 4; nt++)
        #pragma unroll
        for (int mt = 0; mt < 4; mt++) acc[nt][mt] = zz;

    int aoff = ((wn >> 4)) * 512 + q * 128 + l16 * 8;
    int boff = ((wm >> 4)) * 512 + q * 128 + l16 * 8;

    for (int ks = 0; ks < 16; ks++) {
        int buf = ks & 1;
        _Float16* Axc = Ax0 + buf * 4096;
        _Float16* Bxc = Bx0 + buf * 4096;
        fp16x8 a0n, a1n, b0n, b1n;
        if (ks < 15) {
            a0n = *(const fp16x8*)(gA + (ks + 1) * 512);
            a1n = *(const fp16x8*)(gA + (ks + 1) * 512 + 8);
            b0n = *(const fp16x8*)(gB + (ks + 1) * 512);
            b1n = *(const fp16x8*)(gB + (ks + 1) * 512 + 8);
        }

        fp16x8 afr[4], bfr[4];
        #pragma unroll
        for (int nt = 0; nt < 4; nt++)
            afr[nt] = *(const fp16x8*)&Axc[aoff + nt * 512];
        #pragma unroll
        for (int mt = 0; mt < 4; mt++)
            bfr[mt] = *(const fp16x8*)&Bxc[boff + mt * 512];
        #pragma unroll
        for (int nt = 0; nt < 4; nt++)
            #pragma unroll
            for (int mt = 0; mt < 4; mt++)
                acc[nt][mt] = __builtin_amdgcn_mfma_f32_16x16x32_f16(afr[nt], bfr[mt], acc[nt][mt], 0, 0, 0);

        if (ks < 15) {
            _Float16* Axn = Ax0 + (buf ^ 1) * 4096;
            _Float16* Bxn = Bx0 + (buf ^ 1) * 4096;
            *(fp16x8*)&Axn[tid * 16] = a0n; *(fp16x8*)&Axn[tid * 16 + 8] = a1n;
            *(fp16x8*)&Bxn[tid * 16] = b0n; *(fp16x8*)&Bxn[tid * 16 + 8] = b1n;
        }
        __syncthreads();
    }

    // ---- epilogue: + t[m], per-row tile max / exp / sum ----
    float tv[4];
    #pragma unroll
    for (int mt = 0; mt < 4; mt++) tv[mt] = tG[b * HW + m0 + wm + mt * 16 + l16];
    #pragma unroll
    for (int nt = 0; nt < 4; nt++)
        #pragma unroll
        for (int mt = 0; mt < 4; mt++)
            #pragma unroll
            for (int reg = 0; reg < 4; reg++) acc[nt][mt][reg] += tv[mt];

    float rm[4][4], sum[4][4];
    #pragma unroll
    for (int nt = 0; nt < 4; nt++)
        #pragma unroll
        for (int reg = 0; reg < 4; reg++)
            rm[nt][reg] = fmaxf(fmaxf(acc[nt][0][reg], acc[nt][1][reg]),
                                fmaxf(acc[nt][2][reg], acc[nt][3][reg]));
    #pragma unroll
    for (int s = 1; s < 16; s <<= 1)
        #pragma unroll
        for (int nt = 0; nt < 4; nt++)
            #pragma unroll
            for (int reg = 0; reg < 4; reg++)
                rm[nt][reg] = fmaxf(rm[nt][reg], __shfl_xor(rm[nt][reg], s));
    #pragma unroll
    for (int nt = 0; nt < 4; nt++)
        #pragma unroll
        for (int reg = 0; reg < 4; reg++) sum[nt][reg] = 0.f;
    #pragma unroll
    for (int nt = 0; nt < 4; nt++)
        #pragma unroll
        for (int mt = 0; mt < 4; mt++)
            #pragma unroll
            for (int reg = 0; reg < 4; reg++) {
                float pv = __expf(acc[nt][mt][reg] - rm[nt][reg]);
                acc[nt][mt][reg] = pv;
                sum[nt][reg] += pv;
            }
    #pragma unroll
    for (int s = 1; s < 16; s <<= 1)
        #pragma unroll
        for (int nt = 0; nt < 4; nt++)
            #pragma unroll
            for (int reg = 0; reg < 4; reg++)
                sum[nt][reg] += __shfl_xor(sum[nt][reg], s);

    int tl = (m0 + wm) >> 6;
    if (l16 == 0) {
        #pragma unroll
        for (int nt = 0; nt < 4; nt++)
            #pragma unroll
            for (int reg = 0; reg < 4; reg++)
                ML[((size_t)(b * HW + n0 + wn + nt * 16 + q * 4 + reg)) * 64 + tl] =
                    make_float2(rm[nt][reg], sum[nt][reg]);
    }

    // ---- f16 + LDS transpose-spill (Pl unions lbuf), then 16B stores ----
    _Float16 (*Pl)[64][72] = (_Float16(*)[64][72])lbuf;
    #pragma unroll
    for (int nt = 0; nt < 4; nt++)
        #pragma unroll
        for (int mt = 0; mt < 4; mt++)
            #pragma unroll
            for (int reg = 0; reg < 4; reg++)
                Pl[w][nt * 16 + q * 4 + reg][mt * 16 + l16] = (_Float16)acc[nt][mt][reg];
    __syncthreads();
    _Float16* SgB = Sg + (size_t)b * 16777216;
    #pragma unroll
    for (int i = 0; i < 8; i++) {
        int row = i * 8 + (lane >> 3), c8 = (lane & 7) * 8;
        int n = n0 + wn + row, m = m0 + wm + c8;
        *(fp16x8*)&SgB[SFT_IDX(n, m)] = *(const fp16x8*)&Pl[w][row][c8];
    }
}

// ---------------------------------------------------------------------------
// 5b) per-row global softmax scales: Scl[b][tile][n] = e^(m_tile - M)/L (f32)
// ---------------------------------------------------------------------------
__global__ void __launch_bounds__(256) scale_kernel(char* __restrict__ ws)
{
    const float* __restrict__ mlf0 = (const float*)(ws + OFF_ML);
    float* __restrict__ Scl = (float*)(ws + OFF_XCT);
    __shared__ float mlv[64][129];       // [row][2*tile + {0:max,1:sum}]
    __shared__ float Ms[64], Li[64];

    int g0 = blockIdx.x * 64;            // global row base (b*4096 + n), 16384 total
    int tid = threadIdx.x;
    const float* mlf = mlf0 + (size_t)g0 * 128;   // 64 rows x 128 f32 (float2[64])

    #pragma unroll
    for (int i = 0; i < 8; i++) {
        int f4 = i * 256 + tid;          // 2048 float4 = 64 rows x 32
        int row = f4 >> 5, c4 = (f4 & 31) * 4;
        float4 v = *(const float4*)(mlf + row * 128 + c4);
        mlv[row][c4] = v.x; mlv[row][c4 + 1] = v.y;
        mlv[row][c4 + 2] = v.z; mlv[row][c4 + 3] = v.w;
    }
    __syncthreads();
    if (tid < 64) {
        float M = -1e30f;
        #pragma unroll
        for (int k = 0; k < 64; k++) M = fmaxf(M, mlv[tid][k * 2]);
        float L = 0.f;
        #pragma unroll
        for (int k = 0; k < 64; k++) L += mlv[tid][k * 2 + 1] * __expf(mlv[tid][k * 2] - M);
        Ms[tid] = M; Li[tid] = 1.f / L;
    }
    __syncthreads();
    int b = g0 >> 12, nbase = g0 & 4095;
    float* sp = Scl + (size_t)b * 262144 + nbase;
    int row = tid & 63, tsub = tid >> 6;
    #pragma unroll
    for (int pass = 0; pass < 16; pass++) {
        int tile = pass * 4 + tsub;
        sp[(size_t)tile * 4096 + row] = __expf(mlv[row][tile * 2] - Ms[row]) * Li[row];
    }
}

// ---------------------------------------------------------------------------
// 6) pass C: O = (p * scale) @ Hp^T — LDS-Hp pipeline (unchanged from r6).
// ---------------------------------------------------------------------------
__global__ void __launch_bounds__(256, 4) pv_kernel(const float* __restrict__ xc,
                                                    const float* __restrict__ bo,
                                                    float* __restrict__ out,
                                                    char* __restrict__ ws)
{
    const _Float16* __restrict__ Sft = (const _Float16*)(ws + OFF_S);
    const _Float16* __restrict__ Hp = (const _Float16*)(ws + OFF_HM);
    const float* __restrict__ Scl = (const float*)(ws + OFF_XCT);

    int bx = blockIdx.x;                 // 1024 = 32 ntb * 8 cog * 4 b
    int b = bx & 3, cog = (bx >> 2) & 7, ntb = bx >> 5;
    int co0 = cog * 64;
    int tid = threadIdx.x, w = tid >> 6, lane = tid & 63, q = lane >> 4, l16 = lane & 15;
    int n0w = ntb * 128 + w * 32;

    __shared__ _Float16 Hl[2][4096];     // 8KB chunk slice (64co x 64keys), dbuf

    int ln64 = lane;
    const _Float16* hsrc = Hp + (size_t)b * 2097152
                              + (size_t)((co0 >> 4) + w) * 65536 + ln64 * 8;
    const _Float16* sb = Sft + (size_t)b * 16777216
                             + (size_t)(ntb * 8 + w * 2) * 65536 + q * 128 + l16 * 8;
    const float* sc = Scl + (size_t)b * 262144 + n0w + q * 4;

    // prologue: stage chunk 0
    {
        fp16x8 s0 = *(const fp16x8*)(hsrc);
        fp16x8 s1 = *(const fp16x8*)(hsrc + 512);
        *(fp16x8*)&Hl[0][w * 1024 + ln64 * 8] = s0;
        *(fp16x8*)&Hl[0][w * 1024 + 512 + ln64 * 8] = s1;
    }
    __syncthreads();

    f32x4 zz = {0.f, 0.f, 0.f, 0.f};
    f32x4 acc[2][4];
    #pragma unroll
    for (int nt = 0; nt < 2; nt++)
        #pragma unroll
        for (int ct = 0; ct < 4; ct++) acc[nt][ct] = zz;

    for (int chunk = 0; chunk < 64; chunk++) {
        int buf = chunk & 1;
        fp16x8 s0n, s1n;
        if (chunk < 63) {
            s0n = *(const fp16x8*)(hsrc + (chunk + 1) * 1024);
            s1n = *(const fp16x8*)(hsrc + (chunk + 1) * 1024 + 512);
        }

        f32x4 tmp[2][4];
        #pragma unroll
        for (int km = 0; km < 2; km++) {
            fp16x8 afr[2], bfr[4];
            #pragma unroll
            for (int nt = 0; nt < 2; nt++)
                afr[nt] = *(const fp16x8*)(sb + (size_t)nt * 65536 + (chunk * 2 + km) * 512);
            #pragma unroll
            for (int ct = 0; ct < 4; ct++)
                bfr[ct] = *(const fp16x8*)&Hl[buf][ct * 1024 + (km * 4 + q) * 128 + l16 * 8];
            #pragma unroll
            for (int nt = 0; nt < 2; nt++)
                #pragma unroll
                for (int ct = 0; ct < 4; ct++)
                    tmp[nt][ct] = __builtin_amdgcn_mfma_f32_16x16x32_f16(
                        afr[nt], bfr[km == 0 ? ct : ct], km == 0 ? zz : tmp[nt][ct], 0, 0, 0);
        }
        float4 sv0 = *(const float4*)(sc + chunk * 4096);
        float4 sv1 = *(const float4*)(sc + chunk * 4096 + 16);
        float sva[2][4] = {{sv0.x, sv0.y, sv0.z, sv0.w}, {sv1.x, sv1.y, sv1.z, sv1.w}};
        #pragma unroll
        for (int nt = 0; nt < 2; nt++)
            #pragma unroll
            for (int ct = 0; ct < 4; ct++)
                #pragma unroll
                for (int reg = 0; reg < 4; reg++)
                    acc[nt][ct][reg] += tmp[nt][ct][reg] * sva[nt][reg];

        if (chunk < 63) {
            *(fp16x8*)&Hl[buf ^ 1][w * 1024 + ln64 * 8] = s0n;
            *(fp16x8*)&Hl[buf ^ 1][w * 1024 + 512 + ln64 * 8] = s1n;
        }
        __syncthreads();
    }

    // ---- epilogue: + bo + content ----
    #pragma unroll
    for (int nt = 0; nt < 2; nt++)
        #pragma unroll
        for (int ct = 0; ct < 4; ct++) {
            int co = co0 + ct * 16 + l16;
            size_t base = ((size_t)(b * C + co)) * HW + n0w + nt * 16 + q * 4;
            float4 cv = *(const float4*)&xc[base];
            float bov = bo[co];
            float4 o;
            o.x = acc[nt][ct][0] + bov + cv.x;
            o.y = acc[nt][ct][1] + bov + cv.y;
            o.z = acc[nt][ct][2] + bov + cv.z;
            o.w = acc[nt][ct][3] + bov + cv.w;
            *(float4*)&out[base] = o;
        }
}

// ---------------------------------------------------------------------------
extern "C" void kernel_launch(void* const* d_in, const int* in_sizes, int n_in,
                              void* d_out, int out_size, void* d_ws, size_t ws_size,
                              hipStream_t stream)
{
    const float* content = (const float*)d_in[0];
    const float* style   = (const float*)d_in[1];
    const float* Wf = (const float*)d_in[2];
    const float* bf = (const float*)d_in[3];
    const float* Wg = (const float*)d_in[4];
    // d_in[5] = bg: provably unused (softmax row-constant)
    const float* Wh = (const float*)d_in[6];
    const float* bh = (const float*)d_in[7];
    const float* Wo = (const float*)d_in[8];
    const float* bo = (const float*)d_in[9];
    float* out = (float*)d_out;
    char* ws = (char*)d_ws;

    transpose_stats_kernel<<<4096, 256, 0, stream>>>(content, style, ws);
    finalize_stats_kernel<<<16, 256, 0, stream>>>(ws);
    precompute_kernel<<<512, 256, 0, stream>>>(Wf, Wg, Wo, Wh, ws);
    vecprep_kernel<<<640, 256, 0, stream>>>(Wf, bf, Wo, bh, ws);
    scaleA_kernel<<<128, 256, 0, stream>>>(ws);
    precompute_v_kernel<<<32, 256, 0, stream>>>(Wg, ws);
    prep_gemm_kernel<<<1024, 256, 0, stream>>>(ws);
    t_kernel<<<256, 256, 0, stream>>>(ws);
    qk_kernel<<<4096, 256, 0, stream>>>(ws);
    scale_kernel<<<256, 256, 0, stream>>>(ws);
    pv_kernel<<<1024, 256, 0, stream>>>(content, bo, out, ws);
}

// Round 12
// 471.703 us; speedup vs baseline: 1.0063x; 1.0063x over previous
//
#include <hip/hip_runtime.h>

#define C 512
#define HW 4096
#define EPSV 1e-5f

typedef _Float16 fp16x8 __attribute__((ext_vector_type(8)));
typedef _Float16 fp16x4 __attribute__((ext_vector_type(4)));
typedef float f32x4 __attribute__((ext_vector_type(4)));

// ---- workspace layout (bytes) ----
#define OFF_MC    (0)
#define OFF_RC    (8192)
#define OFF_MS    (16384)
#define OFF_RS    (24576)
#define OFF_BETAF (32768)
#define OFF_V     (40960)
#define OFF_BZ    (49152)
#define OFF_T     (65536)                      // t[b][m] f32, 64 KB
#define OFF_SP    (131072)                     // stats partials (2MB); reused as As f16 after finalize
#define OFF_A     (OFF_SP + 2097152)           // 1 MB (A f32)
#define OFF_WZ    (OFF_A + 1048576)            // 1 MB (Wz f16 FT, 512KB used)
#define OFF_XCT   (OFF_WZ + 1048576)           // 16 MB (fragment-tiled)
#define OFF_XST   (OFF_XCT + 16777216)         // 16 MB (fragment-tiled)
#define OFF_KT    (OFF_XST + 16777216)         // 16 MB (fragment-tiled)
#define OFF_HM    (OFF_KT + 16777216)          // 16 MB (fragment-tiled Hp layout)
#define OFF_ML    (OFF_HM + 16777216)          // float2[4][4096][64] = 8 MB
#define OFF_S     (OFF_ML + 8388608)           // f16 [4] fragment-tiled [4096][4096] = 128 MB
// total ~= 204 MB

// Fragment-tiled layout for transposed f16 tensors (xcT, xsT, Kt) and 512x512
// operands (As, Wz): elem (row n, col c) ->
//   ((n>>4)*16 + (c>>5))*512 + ((c>>3)&3)*128 + (n&15)*8 + (c&7)
#define FT_IDX(n, c) ((((size_t)((n) >> 4) * 16 + ((c) >> 5)) * 512) + \
                      ((((c) >> 3) & 3) * 128) + (((n) & 15) * 8) + ((c) & 7))

// S fragment-tiled (per batch, n,m in [0,4096)):
#define SFT_IDX(n, m) ((((size_t)((n) >> 4) * 128 + ((m) >> 5)) * 512) + \
                       ((((m) >> 3) & 3) * 128) + (((n) & 15) * 8) + ((m) & 7))

// Hp tiled layout (per batch b): (co, m) at ((co>>4)*512 + (m>>3))*128 + (co&15)*8 + (m&7)

// Stats partials: float2 part[64 chunk][4096 ch] (chunk-major, coalesced both sides)

// ---------------------------------------------------------------------------
// 1) fused transpose + f16 cast + partial stats.
// ---------------------------------------------------------------------------
__global__ void transpose_stats_kernel(const float* __restrict__ xc, const float* __restrict__ xs,
                                       char* __restrict__ ws)
{
    int bx = blockIdx.x;                  // 4096 = 2 * 4 * 8 * 64
    int tensor = bx >> 11, b = (bx >> 9) & 3, c0 = ((bx >> 6) & 7) * 64, n0 = (bx & 63) * 64;
    const float* src = tensor ? xs : xc;
    _Float16* dst = (_Float16*)(ws + (tensor ? OFF_XST : OFF_XCT));
    float2* part = (float2*)(ws + OFF_SP);

    __shared__ _Float16 tile[64][72];
    __shared__ float pS[64][16], pSS[64][16];

    int tid = threadIdx.x, w = tid >> 6, lane = tid & 63, cq = lane >> 4, l16 = lane & 15;
    #pragma unroll
    for (int k = 0; k < 4; k++) {
        int cr = w * 16 + k * 4 + cq;                 // c offset within tile
        int nf = l16 * 4;                             // n offset within tile
        float4 v = *(const float4*)(src + ((size_t)(b * C + c0 + cr)) * HW + n0 + nf);
        pS[cr][l16] = v.x + v.y + v.z + v.w;
        pSS[cr][l16] = v.x * v.x + v.y * v.y + v.z * v.z + v.w * v.w;
        tile[nf][cr] = (_Float16)v.x; tile[nf + 1][cr] = (_Float16)v.y;
        tile[nf + 2][cr] = (_Float16)v.z; tile[nf + 3][cr] = (_Float16)v.w;
    }
    __syncthreads();
    if (tid < 64) {
        float S = 0.f, SS = 0.f;
        #pragma unroll
        for (int j = 0; j < 16; j++) { S += pS[tid][j]; SS += pSS[tid][j]; }
        part[((size_t)(n0 >> 6)) * 4096 + (tensor * 4 + b) * 512 + c0 + tid] =
            make_float2(S, SS);
    }
    _Float16* dstB = dst + (size_t)b * HW * C;
    #pragma unroll
    for (int i = 0; i < 2; i++) {
        int g = tid + i * 256, row = g >> 3, c8 = (g & 7) * 8;
        int n = n0 + row, c = c0 + c8;
        *(fp16x8*)&dstB[FT_IDX(n, c)] = *(const fp16x8*)&tile[row][c8];
    }
}

// ---------------------------------------------------------------------------
// S1) stage1: blocks 0..15 finalize stats; 16..527 precompute A / Wz.
// ---------------------------------------------------------------------------
__global__ void __launch_bounds__(256) stage1_kernel(const float* __restrict__ Wf,
                                                     const float* __restrict__ Wg,
                                                     const float* __restrict__ Wo,
                                                     const float* __restrict__ Wh,
                                                     char* __restrict__ ws)
{
    int bx = blockIdx.x, t = threadIdx.x;
    if (bx < 16) {
        // ---- finalize stats (chunk-major partials, coalesced) ----
        int ch = bx * 256 + t;
        const float2* part = (const float2*)(ws + OFF_SP);
        float S = 0.f, SS = 0.f;
        for (int k = 0; k < 64; k++) { float2 v = part[(size_t)k * 4096 + ch]; S += v.x; SS += v.y; }
        int tensor = ch >> 11, rem = ch & 2047;
        float m = S / (float)HW;
        float var = (SS - S * m) / (float)(HW - 1) + EPSV;
        ((float*)(ws + (tensor ? OFF_MS : OFF_MC)))[rem] = m;
        ((float*)(ws + (tensor ? OFF_RS : OFF_RC)))[rem] = rsqrtf(var);
        return;
    }
    // ---- precompute A (f32) / Wz (f16 FT) ----
    float* A = (float*)(ws + OFF_A);
    _Float16* Wz16 = (_Float16*)(ws + OFF_WZ);
    int bx2 = bx - 16;
    bool isA = bx2 < 256;
    int r0 = (isA ? bx2 : bx2 - 256) * 2;
    float a00 = 0.f, a01 = 0.f, a10 = 0.f, a11 = 0.f;
    for (int k = 0; k < C; k++) {
        float r0v, r1v, c0v, c1v;
        if (isA) {
            r0v = Wf[k * C + r0]; r1v = Wf[k * C + r0 + 1];
            c0v = Wg[k * C + t];  c1v = Wg[k * C + t + 256];
        } else {
            r0v = Wo[r0 * C + k]; r1v = Wo[(r0 + 1) * C + k];
            c0v = Wh[k * C + t];  c1v = Wh[k * C + t + 256];
        }
        a00 += r0v * c0v; a01 += r0v * c1v;
        a10 += r1v * c0v; a11 += r1v * c1v;
    }
    if (isA) {
        A[r0 * C + t] = a00;       A[r0 * C + t + 256] = a01;
        A[(r0 + 1) * C + t] = a10; A[(r0 + 1) * C + t + 256] = a11;
    } else {
        Wz16[FT_IDX(r0, t)] = (_Float16)a00;
        Wz16[FT_IDX(r0, t + 256)] = (_Float16)a01;
        Wz16[FT_IDX(r0 + 1, t)] = (_Float16)a10;
        Wz16[FT_IDX(r0 + 1, t + 256)] = (_Float16)a11;
    }
}

// ---------------------------------------------------------------------------
// S2) stage2: blocks 0..639 vecprep (betaf, bz); 640..767 scaleA (As f16 FT).
// ---------------------------------------------------------------------------
__global__ void __launch_bounds__(256) stage2_kernel(const float* __restrict__ Wf,
                                                     const float* __restrict__ bf,
                                                     const float* __restrict__ Wo,
                                                     const float* __restrict__ bh,
                                                     char* __restrict__ ws)
{
    __shared__ float At[16][516];
    __shared__ float rsl[512];
    __shared__ float rcl[16];

    int bx = blockIdx.x, t = threadIdx.x;
    if (bx < 640) {
        // ---- vecprep: one output per wave, coalesced row reads ----
        const float* mc = (const float*)(ws + OFF_MC);
        const float* rc = (const float*)(ws + OFF_RC);
        float* betaf = (float*)(ws + OFF_BETAF);
        float* bz = (float*)(ws + OFF_BZ);
        int o = bx * 4 + (t >> 6);
        int lane = t & 63;
        float acc = 0.f;
        if (o < 2048) {
            int b = o >> 9, co = o & 511;
            const float* wr = Wf + (size_t)co * C + lane * 8;
            const float* mp = mc + b * C + lane * 8;
            const float* rp = rc + b * C + lane * 8;
            #pragma unroll
            for (int e = 0; e < 8; e++) acc += wr[e] * mp[e] * rp[e];
        } else {
            int co = o - 2048;
            const float* wr = Wo + (size_t)co * C + lane * 8;
            const float* bp = bh + lane * 8;
            #pragma unroll
            for (int e = 0; e < 8; e++) acc += wr[e] * bp[e];
        }
        acc += __shfl_xor(acc, 1);
        acc += __shfl_xor(acc, 2);
        acc += __shfl_xor(acc, 4);
        acc += __shfl_xor(acc, 8);
        acc += __shfl_xor(acc, 16);
        acc += __shfl_xor(acc, 32);
        if (lane == 0) {
            if (o < 2048) betaf[o] = bf[o & 511] - acc;
            else bz[o - 2048] = acc;
        }
        return;
    }
    // ---- scaleA: LDS-staged coalesced ----
    {
        const float* __restrict__ A = (const float*)(ws + OFF_A);
        const float* __restrict__ rc = (const float*)(ws + OFF_RC);
        const float* __restrict__ rs = (const float*)(ws + OFF_RS);
        _Float16* __restrict__ As = (_Float16*)(ws + OFF_SP);

        int bx2 = bx - 640;                  // 128 = 4 b * 32 r16-groups
        int b = bx2 >> 5, r16 = bx2 & 31;
        int r0 = r16 * 16;

        rsl[t] = rs[b * C + t];
        rsl[t + 256] = rs[b * C + t + 256];
        if (t < 16) rcl[t] = rc[b * C + r0 + t];
        {
            int row = t >> 4, cb = (t & 15) * 32;
            const float* src = A + (size_t)(r0 + row) * C + cb;
            #pragma unroll
            for (int k = 0; k < 8; k++) {
                float4 v = *(const float4*)(src + k * 4);
                At[row][cb + k * 4] = v.x; At[row][cb + k * 4 + 1] = v.y;
                At[row][cb + k * 4 + 2] = v.z; At[row][cb + k * 4 + 3] = v.w;
            }
        }
        __syncthreads();

        _Float16* AsB = As + (size_t)b * 262144 + (size_t)r16 * 8192;
        #pragma unroll
        for (int round = 0; round < 4; round++) {
            int flat = round * 2048 + t * 8;
            int cb4 = flat >> 9, rem = flat & 511;
            int low6 = rem >> 3;
            int q = low6 >> 4, l16 = low6 & 15;
            int cbase = cb4 * 32 + q * 8;
            float rcv = rcl[l16];
            fp16x8 o;
            #pragma unroll
            for (int e = 0; e < 8; e++)
                o[e] = (_Float16)(At[l16][cbase + e] * rcv * rsl[cbase + e]);
            *(fp16x8*)&AsB[flat] = o;
        }
    }
}

// ---------------------------------------------------------------------------
// 2c) v[b][j] = rs[b][j] * sum_co betaf[b][co]*Wg[co][j] — LDS-tiled.
// ---------------------------------------------------------------------------
__global__ void __launch_bounds__(256) precompute_v_kernel(const float* __restrict__ Wg,
                                                           char* __restrict__ ws)
{
    const float* betaf = (const float*)(ws + OFF_BETAF);
    const float* rs = (const float*)(ws + OFF_RS);
    float* v = (float*)(ws + OFF_V);

    __shared__ float bet[512];
    __shared__ float Wgt[64][68];
    __shared__ float pacc[4][64];
    __shared__ float rsl[64];

    int bx = blockIdx.x;                 // 32 = 4 b * 8 j-groups
    int b = bx >> 3, j0 = (bx & 7) * 64;
    int t = threadIdx.x;

    bet[t] = betaf[b * C + t];
    bet[t + 256] = betaf[b * C + t + 256];
    if (t < 64) rsl[t] = rs[b * C + j0 + t];

    int j = t & 63, g = t >> 6;
    float acc = 0.f;
    for (int ch = 0; ch < 8; ch++) {
        __syncthreads();
        {
            int row = t >> 2, cq = (t & 3) * 16;
            const float* src = Wg + (size_t)(ch * 64 + row) * C + j0 + cq;
            #pragma unroll
            for (int k = 0; k < 4; k++) {
                float4 w4 = *(const float4*)(src + k * 4);
                Wgt[row][cq + k * 4] = w4.x; Wgt[row][cq + k * 4 + 1] = w4.y;
                Wgt[row][cq + k * 4 + 2] = w4.z; Wgt[row][cq + k * 4 + 3] = w4.w;
            }
        }
        __syncthreads();
        #pragma unroll
        for (int r2 = 0; r2 < 16; r2++) {
            int col = g * 16 + r2;
            acc += bet[ch * 64 + col] * Wgt[col][j];
        }
    }
    pacc[g][j] = acc;
    __syncthreads();
    if (t < 64)
        v[b * C + j0 + t] = rsl[t] * (pacc[0][t] + pacc[1][t] + pacc[2][t] + pacc[3][t]);
}

// ---------------------------------------------------------------------------
// S4) stage4: blocks 0..1023 prep GEMM (Kt, Hp); 1024..1279 t-vector.
// ---------------------------------------------------------------------------
__global__ void __launch_bounds__(256) stage4_kernel(char* __restrict__ ws)
{
    if (blockIdx.x >= 1024) {
        // ---- t[b][m] = sum_j v[b][j]*xsT[b][m][j], wave-linear FT loads ----
        const float* v = (const float*)(ws + OFF_V);
        const _Float16* __restrict__ xsT = (const _Float16*)(ws + OFF_XST);
        float* tG = (float*)(ws + OFF_T);
        int bx2 = blockIdx.x - 1024;          // 256 = 4 b * 64 mblk(64m)
        int b = bx2 >> 6, mb = bx2 & 63;
        int tid = threadIdx.x, w = tid >> 6, lane = tid & 63, q = lane >> 4, l16 = lane & 15;
        int M16 = mb * 4 + w;
        const _Float16* p = xsT + (size_t)b * HW * C + (size_t)M16 * 8192 + q * 128 + l16 * 8;
        const float* vp = v + b * C + q * 8;
        float acc = 0.f;
        #pragma unroll
        for (int st = 0; st < 16; st++) {
            fp16x8 xv = *(const fp16x8*)(p + st * 512);
            float4 v0 = *(const float4*)(vp + st * 32);
            float4 v1 = *(const float4*)(vp + st * 32 + 4);
            acc += (float)xv[0] * v0.x + (float)xv[1] * v0.y + (float)xv[2] * v0.z + (float)xv[3] * v0.w
                 + (float)xv[4] * v1.x + (float)xv[5] * v1.y + (float)xv[6] * v1.z + (float)xv[7] * v1.w;
        }
        acc += __shfl_xor(acc, 16);
        acc += __shfl_xor(acc, 32);
        if (q == 0) tG[b * HW + M16 * 16 + l16] = acc;
        return;
    }
    // ---- prep GEMM ----
    const _Float16* __restrict__ As = (const _Float16*)(ws + OFF_SP);
    const _Float16* __restrict__ Wz16 = (const _Float16*)(ws + OFF_WZ);
    const float* __restrict__ bz = (const float*)(ws + OFF_BZ);
    const _Float16* __restrict__ xsT = (const _Float16*)(ws + OFF_XST);
    _Float16* __restrict__ Kt = (_Float16*)(ws + OFF_KT);
    _Float16* __restrict__ Hp = (_Float16*)(ws + OFF_HM);

    int bx = blockIdx.x;                 // 1024 = 4b * 8 rowblk * 32 mblk
    int b = bx & 3, rest = bx >> 2;
    int r128 = rest >> 5, mb = rest & 31;
    int r0 = r128 * 128, m0 = mb * 128;
    int w = threadIdx.x >> 6, lane = threadIdx.x & 63, q = lane >> 4, l16 = lane & 15;
    int wr = (w & 1) * 64, wm = (w >> 1) * 64;
    bool isK = (r0 < 512);
    int rbase = (isK ? r0 : r0 - 512) + wr;

    f32x4 zz = {0.f, 0.f, 0.f, 0.f};
    f32x4 acc[4][4];
    #pragma unroll
    for (int rt = 0; rt < 4; rt++)
        #pragma unroll
        for (int mt = 0; mt < 4; mt++) acc[rt][mt] = zz;

    const _Float16* ap = (isK ? As + (size_t)b * 262144 : Wz16)
                         + (size_t)(rbase >> 4) * 8192 + q * 128 + l16 * 8;
    const _Float16* xb = xsT + (size_t)b * HW * C
                             + (size_t)((m0 + wm) >> 4) * 8192 + q * 128 + l16 * 8;

    for (int ks = 0; ks < 16; ks++) {
        fp16x8 afr[4], bfr[4];
        #pragma unroll
        for (int rt = 0; rt < 4; rt++)
            afr[rt] = *(const fp16x8*)(ap + (size_t)rt * 8192 + ks * 512);
        #pragma unroll
        for (int mt = 0; mt < 4; mt++)
            bfr[mt] = *(const fp16x8*)(xb + (size_t)(mt * 16 + ks) * 512);
        #pragma unroll
        for (int rt = 0; rt < 4; rt++)
            #pragma unroll
            for (int mt = 0; mt < 4; mt++)
                acc[rt][mt] = __builtin_amdgcn_mfma_f32_16x16x32_f16(afr[rt], bfr[mt], acc[rt][mt], 0, 0, 0);
    }

    if (isK) {
        _Float16* KtB = Kt + (size_t)b * HW * C;
        #pragma unroll
        for (int rt = 0; rt < 4; rt++)
            #pragma unroll
            for (int mt = 0; mt < 4; mt++) {
                int m = m0 + wm + mt * 16 + l16;
                int cb = r0 + wr + rt * 16 + q * 4;
                fp16x4 h;
                h[0] = (_Float16)acc[rt][mt][0]; h[1] = (_Float16)acc[rt][mt][1];
                h[2] = (_Float16)acc[rt][mt][2]; h[3] = (_Float16)acc[rt][mt][3];
                *(fp16x4*)&KtB[FT_IDX(m, cb)] = h;
            }
    } else {
        _Float16* HpB = Hp + (size_t)b * 2097152;
        #pragma unroll
        for (int rt = 0; rt < 4; rt++) {
            float bzv[4];
            #pragma unroll
            for (int reg = 0; reg < 4; reg++) bzv[reg] = bz[rbase + rt * 16 + q * 4 + reg];
            #pragma unroll
            for (int mt = 0; mt < 4; mt++) {
                int m = m0 + wm + mt * 16 + l16;
                int mbase = (m >> 3) * 128 + (m & 7);
                #pragma unroll
                for (int reg = 0; reg < 4; reg++) {
                    int co = rbase + rt * 16 + q * 4 + reg;
                    HpB[(size_t)(co >> 4) * 65536 + mbase + (co & 15) * 8] =
                        (_Float16)(acc[rt][mt][reg] + bzv[reg]);
                }
            }
        }
    }
}

// ---------------------------------------------------------------------------
// 5) pass A: S-tile = Q @ Kt^T (128x128, K=512) + t[m], LDS-STAGED (r10).
// ---------------------------------------------------------------------------
__global__ void __launch_bounds__(256, 4) qk_kernel(char* __restrict__ ws)
{
    const _Float16* __restrict__ xcT = (const _Float16*)(ws + OFF_XCT);
    const _Float16* __restrict__ Kt = (const _Float16*)(ws + OFF_KT);
    const float* __restrict__ tG = (const float*)(ws + OFF_T);
    float2* __restrict__ ML = (float2*)(ws + OFF_ML);
    _Float16* __restrict__ Sg = (_Float16*)(ws + OFF_S);

    int bx = blockIdx.x;                  // 4096: low3 = b*2+mhi (XCD-pinned)
    int b = (bx >> 1) & 3, mhi = bx & 1;
    int rest = bx >> 3, mlo = rest & 15, ntile = rest >> 4;
    int m0 = (mhi * 16 + mlo) * 128, n0 = ntile * 128;
    int tid = threadIdx.x, w = tid >> 6, lane = tid & 63, q = lane >> 4, l16 = lane & 15;
    int wn = (w & 1) * 64, wm = (w >> 1) * 64;

    __shared__ char lbuf[36864];          // loop: Ax[2][8KB]+Bx[2][8KB]; epilogue: Pl
    _Float16* Ax0 = (_Float16*)lbuf;                  // [2][4096]
    _Float16* Bx0 = (_Float16*)(lbuf + 16384);        // [2][4096]

    int st = tid >> 5, so = (tid & 31) * 16;
    const _Float16* gA = xcT + (size_t)b * HW * C + ((size_t)(n0 >> 4) + st) * 8192 + so;
    const _Float16* gB = Kt + (size_t)b * HW * C + ((size_t)(m0 >> 4) + st) * 8192 + so;

    {
        fp16x8 a0 = *(const fp16x8*)(gA);
        fp16x8 a1 = *(const fp16x8*)(gA + 8);
        fp16x8 b0 = *(const fp16x8*)(gB);
        fp16x8 b1 = *(const fp16x8*)(gB + 8);
        *(fp16x8*)&Ax0[tid * 16] = a0; *(fp16x8*)&Ax0[tid * 16 + 8] = a1;
        *(fp16x8*)&Bx0[tid * 16] = b0; *(fp16x8*)&Bx0[tid * 16 + 8] = b1;
    }
    __syncthreads();

    f32x4 zz = {0.f, 0.f, 0.f, 0.f};
    f32x4 acc[4][4];
    #pragma unroll
    for (int nt = 0; nt < 4; nt++)
        #pragma unroll
        for (int mt = 0; mt < 4; mt++) acc[nt][mt] = zz;

    int aoff = ((wn >> 4)) * 512 + q * 128 + l16 * 8;
    int boff = ((wm >> 4)) * 512 + q * 128 + l16 * 8;

    for (int ks = 0; ks < 16; ks++) {
        int buf = ks & 1;
        _Float16* Axc = Ax0 + buf * 4096;
        _Float16* Bxc = Bx0 + buf * 4096;
        fp16x8 a0n, a1n, b0n, b1n;
        if (ks < 15) {
            a0n = *(const fp16x8*)(gA + (ks + 1) * 512);
            a1n = *(const fp16x8*)(gA + (ks + 1) * 512 + 8);
            b0n = *(const fp16x8*)(gB + (ks + 1) * 512);
            b1n = *(const fp16x8*)(gB + (ks + 1) * 512 + 8);
        }

        fp16x8 afr[4], bfr[4];
        #pragma unroll
        for (int nt = 0; nt < 4; nt++)
            afr[nt] = *(const fp16x8*)&Axc[aoff + nt * 512];
        #pragma unroll
        for (int mt = 0; mt < 4; mt++)
            bfr[mt] = *(const fp16x8*)&Bxc[boff + mt * 512];
        #pragma unroll
        for (int nt = 0; nt < 4; nt++)
            #pragma unroll
            for (int mt = 0; mt < 4; mt++)
                acc[nt][mt] = __builtin_amdgcn_mfma_f32_16x16x32_f16(afr[nt], bfr[mt], acc[nt][mt], 0, 0, 0);

        if (ks < 15) {
            _Float16* Axn = Ax0 + (buf ^ 1) * 4096;
            _Float16* Bxn = Bx0 + (buf ^ 1) * 4096;
            *(fp16x8*)&Axn[tid * 16] = a0n; *(fp16x8*)&Axn[tid * 16 + 8] = a1n;
            *(fp16x8*)&Bxn[tid * 16] = b0n; *(fp16x8*)&Bxn[tid * 16 + 8] = b1n;
        }
        __syncthreads();
    }

    // ---- epilogue: + t[m], per-row tile max / exp / sum ----
    float tv[4];
    #pragma unroll
    for (int mt = 0; mt < 4; mt++) tv[mt] = tG[b * HW + m0 + wm + mt * 16 + l16];
    #pragma unroll
    for (int nt = 0; nt < 4; nt++)
        #pragma unroll
        for (int mt = 0; mt < 4; mt++)
            #pragma unroll
            for (int reg = 0; reg < 4; reg++) acc[nt][mt][reg] += tv[mt];

    float rm[4][4], sum[4][4];
    #pragma unroll
    for (int nt = 0; nt < 4; nt++)
        #pragma unroll
        for (int reg = 0; reg < 4; reg++)
            rm[nt][reg] = fmaxf(fmaxf(acc[nt][0][reg], acc[nt][1][reg]),
                                fmaxf(acc[nt][2][reg], acc[nt][3][reg]));
    #pragma unroll
    for (int s = 1; s < 16; s <<= 1)
        #pragma unroll
        for (int nt = 0; nt < 4; nt++)
            #pragma unroll
            for (int reg = 0; reg < 4; reg++)
                rm[nt][reg] = fmaxf(rm[nt][reg], __shfl_xor(rm[nt][reg], s));
    #pragma unroll
    for (int nt = 0; nt < 4; nt++)
        #pragma unroll
        for (int reg = 0; reg < 4; reg++) sum[nt][reg] = 0.f;
    #pragma unroll
    for (int nt = 0; nt < 4; nt++)
        #pragma unroll
        for (int mt = 0; mt < 4; mt++)
            #pragma unroll
            for (int reg = 0; reg < 4; reg++) {
                float pv = __expf(acc[nt][mt][reg] - rm[nt][reg]);
                acc[nt][mt][reg] = pv;
                sum[nt][reg] += pv;
            }
    #pragma unroll
    for (int s = 1; s < 16; s <<= 1)
        #pragma unroll
        for (int nt = 0; nt < 4; nt++)
            #pragma unroll
            for (int reg = 0; reg < 4; reg++)
                sum[nt][reg] += __shfl_xor(sum[nt][reg], s);

    int tl = (m0 + wm) >> 6;
    if (l16 == 0) {
        #pragma unroll
        for (int nt = 0; nt < 4; nt++)
            #pragma unroll
            for (int reg = 0; reg < 4; reg++)
                ML[((size_t)(b * HW + n0 + wn + nt * 16 + q * 4 + reg)) * 64 + tl] =
                    make_float2(rm[nt][reg], sum[nt][reg]);
    }

    // ---- f16 + LDS transpose-spill (Pl unions lbuf), then 16B stores ----
    _Float16 (*Pl)[64][72] = (_Float16(*)[64][72])lbuf;
    #pragma unroll
    for (int nt = 0; nt < 4; nt++)
        #pragma unroll
        for (int mt = 0; mt < 4; mt++)
            #pragma unroll
            for (int reg = 0; reg < 4; reg++)
                Pl[w][nt * 16 + q * 4 + reg][mt * 16 + l16] = (_Float16)acc[nt][mt][reg];
    __syncthreads();
    _Float16* SgB = Sg + (size_t)b * 16777216;
    #pragma unroll
    for (int i = 0; i < 8; i++) {
        int row = i * 8 + (lane >> 3), c8 = (lane & 7) * 8;
        int n = n0 + wn + row, m = m0 + wm + c8;
        *(fp16x8*)&SgB[SFT_IDX(n, m)] = *(const fp16x8*)&Pl[w][row][c8];
    }
}

// ---------------------------------------------------------------------------
// 6) pass C: O = (p * scale) @ Hp^T — LDS-Hp pipeline, softmax scales
//    computed INLINE in the prologue from ML (f16 SclH, pre-r5 pattern).
// ---------------------------------------------------------------------------
__global__ void __launch_bounds__(256, 4) pv_kernel(const float* __restrict__ xc,
                                                    const float* __restrict__ bo,
                                                    float* __restrict__ out,
                                                    char* __restrict__ ws)
{
    const _Float16* __restrict__ Sft = (const _Float16*)(ws + OFF_S);
    const _Float16* __restrict__ Hp = (const _Float16*)(ws + OFF_HM);
    const float2* __restrict__ ML = (const float2*)(ws + OFF_ML);

    int bx = blockIdx.x;                 // 1024 = 32 ntb * 8 cog * 4 b
    int b = bx & 3, cog = (bx >> 2) & 7, ntb = bx >> 5;
    int co0 = cog * 64;
    int tid = threadIdx.x, w = tid >> 6, lane = tid & 63, q = lane >> 4, l16 = lane & 15;
    int n0w = ntb * 128 + w * 32;

    __shared__ _Float16 Hl[2][4096];     // 8KB chunk slice (64co x 64keys), dbuf
    __shared__ _Float16 SclH[64][132];   // [tile][row-in-block], f16 scales

    // ---- prologue A: inline softmax scales for the block's 128 rows ----
    {
        int row = tid >> 1, part = tid & 1;       // 2 threads per row, 32 tiles each
        const float2* mlp = ML + ((size_t)(b * HW + ntb * 128 + row)) * 64 + part * 32;
        float M = -1e30f;
        #pragma unroll
        for (int k = 0; k < 32; k += 4) {
            float4 a = *(const float4*)(mlp + k);
            float4 c = *(const float4*)(mlp + k + 2);
            M = fmaxf(M, fmaxf(fmaxf(a.x, a.z), fmaxf(c.x, c.z)));
        }
        M = fmaxf(M, __shfl_xor(M, 1));           // combine the 2 halves
        float L = 0.f;
        #pragma unroll
        for (int k = 0; k < 32; k += 2) {
            float4 a = *(const float4*)(mlp + k);
            L += a.y * __expf(a.x - M) + a.w * __expf(a.z - M);
        }
        L += __shfl_xor(L, 1);
        float linv = 1.f / L;
        #pragma unroll
        for (int k = 0; k < 32; k += 2) {
            float4 a = *(const float4*)(mlp + k);
            SclH[part * 32 + k][row] = (_Float16)(__expf(a.x - M) * linv);
            SclH[part * 32 + k + 1][row] = (_Float16)(__expf(a.z - M) * linv);
        }
    }

    int ln64 = lane;
    const _Float16* hsrc = Hp + (size_t)b * 2097152
                              + (size_t)((co0 >> 4) + w) * 65536 + ln64 * 8;
    const _Float16* sb = Sft + (size_t)b * 16777216
                             + (size_t)(ntb * 8 + w * 2) * 65536 + q * 128 + l16 * 8;

    // ---- prologue B: stage chunk 0 ----
    {
        fp16x8 s0 = *(const fp16x8*)(hsrc);
        fp16x8 s1 = *(const fp16x8*)(hsrc + 512);
        *(fp16x8*)&Hl[0][w * 1024 + ln64 * 8] = s0;
        *(fp16x8*)&Hl[0][w * 1024 + 512 + ln64 * 8] = s1;
    }
    __syncthreads();

    f32x4 zz = {0.f, 0.f, 0.f, 0.f};
    f32x4 acc[2][4];
    #pragma unroll
    for (int nt = 0; nt < 2; nt++)
        #pragma unroll
        for (int ct = 0; ct < 4; ct++) acc[nt][ct] = zz;

    for (int chunk = 0; chunk < 64; chunk++) {
        int buf = chunk & 1;
        fp16x8 s0n, s1n;
        if (chunk < 63) {
            s0n = *(const fp16x8*)(hsrc + (chunk + 1) * 1024);
            s1n = *(const fp16x8*)(hsrc + (chunk + 1) * 1024 + 512);
        }

        f32x4 tmp[2][4];
        #pragma unroll
        for (int km = 0; km < 2; km++) {
            fp16x8 afr[2], bfr[4];
            #pragma unroll
            for (int nt = 0; nt < 2; nt++)
                afr[nt] = *(const fp16x8*)(sb + (size_t)nt * 65536 + (chunk * 2 + km) * 512);
            #pragma unroll
            for (int ct = 0; ct < 4; ct++)
                bfr[ct] = *(const fp16x8*)&Hl[buf][ct * 1024 + (km * 4 + q) * 128 + l16 * 8];
            #pragma unroll
            for (int nt = 0; nt < 2; nt++)
                #pragma unroll
                for (int ct = 0; ct < 4; ct++)
                    tmp[nt][ct] = __builtin_amdgcn_mfma_f32_16x16x32_f16(
                        afr[nt], bfr[ct], km == 0 ? zz : tmp[nt][ct], 0, 0, 0);
        }
        // f32 scale-accumulate: scales broadcast from LDS (row = w*32 + nt*16 + q*4 + reg)
        fp16x4 svh0 = *(const fp16x4*)&SclH[chunk][w * 32 + q * 4];
        fp16x4 svh1 = *(const fp16x4*)&SclH[chunk][w * 32 + 16 + q * 4];
        float sva[2][4] = {{(float)svh0[0], (float)svh0[1], (float)svh0[2], (float)svh0[3]},
                           {(float)svh1[0], (float)svh1[1], (float)svh1[2], (float)svh1[3]}};
        #pragma unroll
        for (int nt = 0; nt < 2; nt++)
            #pragma unroll
            for (int ct = 0; ct < 4; ct++)
                #pragma unroll
                for (int reg = 0; reg < 4; reg++)
                    acc[nt][ct][reg] += tmp[nt][ct][reg] * sva[nt][reg];

        if (chunk < 63) {
            *(fp16x8*)&Hl[buf ^ 1][w * 1024 + ln64 * 8] = s0n;
            *(fp16x8*)&Hl[buf ^ 1][w * 1024 + 512 + ln64 * 8] = s1n;
        }
        __syncthreads();
    }

    // ---- epilogue: + bo + content ----
    #pragma unroll
    for (int nt = 0; nt < 2; nt++)
        #pragma unroll
        for (int ct = 0; ct < 4; ct++) {
            int co = co0 + ct * 16 + l16;
            size_t base = ((size_t)(b * C + co)) * HW + n0w + nt * 16 + q * 4;
            float4 cv = *(const float4*)&xc[base];
            float bov = bo[co];
            float4 o;
            o.x = acc[nt][ct][0] + bov + cv.x;
            o.y = acc[nt][ct][1] + bov + cv.y;
            o.z = acc[nt][ct][2] + bov + cv.z;
            o.w = acc[nt][ct][3] + bov + cv.w;
            *(float4*)&out[base] = o;
        }
}

// ---------------------------------------------------------------------------
extern "C" void kernel_launch(void* const* d_in, const int* in_sizes, int n_in,
                              void* d_out, int out_size, void* d_ws, size_t ws_size,
                              hipStream_t stream)
{
    const float* content = (const float*)d_in[0];
    const float* style   = (const float*)d_in[1];
    const float* Wf = (const float*)d_in[2];
    const float* bf = (const float*)d_in[3];
    const float* Wg = (const float*)d_in[4];
    // d_in[5] = bg: provably unused (softmax row-constant)
    const float* Wh = (const float*)d_in[6];
    const float* bh = (const float*)d_in[7];
    const float* Wo = (const float*)d_in[8];
    const float* bo = (const float*)d_in[9];
    float* out = (float*)d_out;
    char* ws = (char*)d_ws;

    transpose_stats_kernel<<<4096, 256, 0, stream>>>(content, style, ws);
    stage1_kernel<<<528, 256, 0, stream>>>(Wf, Wg, Wo, Wh, ws);
    stage2_kernel<<<768, 256, 0, stream>>>(Wf, bf, Wo, bh, ws);
    precompute_v_kernel<<<32, 256, 0, stream>>>(Wg, ws);
    stage4_kernel<<<1280, 256, 0, stream>>>(ws);
    qk_kernel<<<4096, 256, 0, stream>>>(ws);
    pv_kernel<<<1024, 256, 0, stream>>>(content, bo, out, ws);
}